// Round 1
// baseline (63.822 us; speedup 1.0000x reference)
//
#include <hip/hip_runtime.h>
#include <math.h>

#define RES   64
#define NPTS  (RES * RES)   // 4096 grid points
#define NB    4             // batches
#define NN    128           // components per batch
#define NP    16            // points per component
#define STRIDE 36           // padded floats per comp in LDS (144 B, 16B-aligned;
                            // wave's 8 concurrent b128 reads -> 8 distinct bank groups)
#define PTS_PER_BLK 32      // half a grid row (uniform x0)
#define NSLICE 4            // component slices per batch
#define NCOMP_BLK 32        // components per block (NN / NSLICE)

// ---------------------------------------------------------------------------
// Kernel A: compute w2[b,n] once per component (was recomputed 128x per batch)
// and zero the output buffer (replaces a memset node; out is atomically
// accumulated by kernel B across the 4 component slices).
// 8 blocks x 64 threads = 512 threads, one (b,n) each.
// ---------------------------------------------------------------------------
__global__ __launch_bounds__(64)
void w2_kernel(const float* __restrict__ Bs, const float* __restrict__ Ds,
               float* __restrict__ w2, float* __restrict__ out) {
    const int tid = blockIdx.x * 64 + threadIdx.x;   // 0..511 == b*128 + n

    // zero out[16384]: coalesced, fire-and-forget stores
    #pragma unroll
    for (int k = 0; k < 32; ++k) out[tid + 512 * k] = 0.0f;

    const float4* B4 = (const float4*)Bs + (size_t)tid * 8;
    const float4* D4 = (const float4*)Ds + (size_t)tid * 8;
    float b0[NP], b1[NP], d0[NP], d1[NP];
    #pragma unroll
    for (int q = 0; q < 8; ++q) {
        float4 f = B4[q];
        b0[2*q] = f.x; b1[2*q] = f.y; b0[2*q+1] = f.z; b1[2*q+1] = f.w;
        f = D4[q];
        d0[2*q] = f.x; d1[2*q] = f.y; d0[2*q+1] = f.z; d1[2*q+1] = f.w;
    }
    // w = max over 256 (i,j) pairs of relu(min(d0-b0, d1-b1)); relu folded
    // into the max-with-0 init (min/relu commute: monotone).
    float w = 0.0f;
    #pragma unroll
    for (int j = 0; j < NP; ++j) {
        #pragma unroll
        for (int i = 0; i < NP; ++i)
            w = fmaxf(w, fminf(d0[j] - b0[i], d1[j] - b1[i]));
    }
    if (!isfinite(w)) w = 0.0f;
    w2[tid] = w * w;
}

// ---------------------------------------------------------------------------
// Kernel B: main accumulation, sharded by component slice for occupancy.
// Grid = 4 batches x 128 point-blocks x 4 slices = 2048 blocks x 256 thr
//      = 8192 waves = 32 waves/CU (was 2048 waves = 8/CU).
// LDS ~13.4 KB/block -> 8 blocks/CU fits (107 KB of 160 KB).
// Each thread: 4 grid points x 1 component (4 pairs).
// ---------------------------------------------------------------------------
__global__ __launch_bounds__(256, 8)
void main_kernel(const float* __restrict__ Bs, const float* __restrict__ Ds,
                 const float* __restrict__ w2, float* __restrict__ out) {
    __shared__ __align__(16) float sB[NCOMP_BLK * STRIDE];   // 4.6 KB
    __shared__ __align__(16) float sD[NCOMP_BLK * STRIDE];   // 4.6 KB
    __shared__ float psum[NCOMP_BLK][PTS_PER_BLK + 1];       // 4.2 KB, +1 pad

    const int bid   = blockIdx.x;
    const int b     = bid >> 9;          // 512 blocks per batch
    const int pblk  = (bid >> 2) & 127;  // 32-point block
    const int slice = bid & 3;           // component slice
    const int t     = threadIdx.x;       // 0..255

    // ---- stage this slice's 32 comps: 4 KB per array, 1 float4/thread ----
    {
        const int comp0 = b * NN + slice * NCOMP_BLK;
        const float4* gB = (const float4*)Bs + (size_t)comp0 * 8;
        const float4* gD = (const float4*)Ds + (size_t)comp0 * 8;
        const int off = (t >> 3) * STRIDE + (t & 7) * 4;     // padded, 16B-aligned
        *(float4*)(sB + off) = gB[t];
        *(float4*)(sD + off) = gD[t];
    }
    __syncthreads();

    const int g = t & 7;                 // point group (4 pts)
    const int c = t >> 3;                // local component 0..31
    const float w2n = w2[b * NN + slice * NCOMP_BLK + c];    // L2-resident

    const int p0 = pblk * PTS_PER_BLK + 4 * g;
    const int i0 = p0 >> 6;              // block-uniform row -> uniform x0
    const float x0 = -3.0f + 6.0f * (float)i0 / 63.0f;
    float x1v[4];
    #pragma unroll
    for (int j = 0; j < 4; ++j)
        x1v[j] = -3.0f + 6.0f * (float)((p0 + j) & 63) / 63.0f;

    // wave: c = lane>>3 -> 8 distinct comps, 8-lane broadcast; comp stride
    // 144 B -> bank groups 0,4,...,28: conflict-free b128 reads.
    const float4* B4 = (const float4*)(sB + c * STRIDE);
    const float4* D4 = (const float4*)(sD + c * STRIDE);
    float db[4] = {1e30f, 1e30f, 1e30f, 1e30f};
    float dd[4] = {1e30f, 1e30f, 1e30f, 1e30f};
    #pragma unroll
    for (int q = 0; q < 8; ++q) {        // 2 boundary points per float4
        const float4 fb = B4[q];
        const float4 fd = D4[q];
        float s  = fb.x - x0;            // shared across the 4 grid points
        float sd = x0 - fd.x;
        #pragma unroll
        for (int j = 0; j < 4; ++j) {
            db[j] = fminf(db[j], fmaxf(s,  fb.y - x1v[j]));
            dd[j] = fminf(dd[j], fmaxf(sd, x1v[j] - fd.y));
        }
        s  = fb.z - x0;
        sd = x0 - fd.z;
        #pragma unroll
        for (int j = 0; j < 4; ++j) {
            db[j] = fminf(db[j], fmaxf(s,  fb.w - x1v[j]));
            dd[j] = fminf(dd[j], fmaxf(sd, x1v[j] - fd.w));
        }
    }
    const float cexp = -0.5f / (0.3f * 0.3f);
    #pragma unroll
    for (int j = 0; j < 4; ++j) {
        const float r = fmaxf(fmaxf(db[j], dd[j]), 0.0f);
        // scalar stores, pad 33: 2-way bank aliasing only (free on CDNA4)
        psum[c][4 * g + j] = __expf(cexp * r * r) * w2n;
    }
    __syncthreads();

    // column read q*33 + t: banks (q+t)%32 -> conflict-free
    if (t < PTS_PER_BLK) {
        float ssum = 0.0f;
        #pragma unroll
        for (int q = 0; q < NCOMP_BLK; ++q) ssum += psum[q][t];
        atomicAdd(&out[(size_t)b * NPTS + pblk * PTS_PER_BLK + t], ssum);
    }
}

extern "C" void kernel_launch(void* const* d_in, const int* in_sizes, int n_in,
                              void* d_out, int out_size, void* d_ws, size_t ws_size,
                              hipStream_t stream) {
    const float* Bs = (const float*)d_in[0];
    const float* Ds = (const float*)d_in[1];
    float* out = (float*)d_out;
    float* w2  = (float*)d_ws;   // 512 floats of workspace

    w2_kernel<<<dim3(8), dim3(64), 0, stream>>>(Bs, Ds, w2, out);
    main_kernel<<<dim3(NB * 128 * NSLICE), dim3(256), 0, stream>>>(Bs, Ds, w2, out);
}

// Round 2
// 61.954 us; speedup vs baseline: 1.0301x; 1.0301x over previous
//
#include <hip/hip_runtime.h>
#include <math.h>

#define RES   64
#define NPTS  (RES * RES)   // 4096 grid points
#define NB    4             // batches
#define NN    128           // components per batch
#define NP    16            // points per component
#define STRIDE 36           // padded floats per comp in LDS (144 B, 16B-aligned;
                            // wave's 8 concurrent b128 reads -> 8 distinct bank groups)
#define PTS_PER_BLK 32      // half a grid row (uniform x0)

// ---------------------------------------------------------------------------
// ONE launch (per-launch overhead ~8us dominated the controllable budget).
// 512 blocks x 1024 threads = 16 waves/block, 2 blocks/CU resident
// (LDS 55KB -> 110KB/CU) = 32 waves/CU = 8 waves/SIMD (4x the old fused
// kernel's 2/SIMD). Each block: all 128 comps x 32 grid points.
// Thread t: comp n = t>>3 (128), point-group g = t&7 (4 pts each).
// ---------------------------------------------------------------------------
__global__ __launch_bounds__(1024, 8)
void fused_kernel(const float* __restrict__ Bs, const float* __restrict__ Ds,
                  float* __restrict__ out) {
    __shared__ __align__(16) float sB[NN * STRIDE];      // 18 KB
    __shared__ __align__(16) float sD[NN * STRIDE];      // 18 KB
    __shared__ float sW2[NN];                            // 0.5 KB
    __shared__ float psum[NN][PTS_PER_BLK + 1];          // 16.5 KB, +1 pad
    __shared__ float pp[8][PTS_PER_BLK + 1];             // 1 KB

    const int bid  = blockIdx.x;
    const int b    = bid >> 7;          // batch
    const int pblk = bid & 127;         // 32-point block (half grid row)
    const int t    = threadIdx.x;       // 0..1023

    // ---- stage global -> LDS: 1024 float4 per array, exactly 1 per thread ----
    {
        const float4* gB = (const float4*)(Bs + (size_t)b * NN * NP * 2);
        const float4* gD = (const float4*)(Ds + (size_t)b * NN * NP * 2);
        const int off = (t >> 3) * STRIDE + (t & 7) * 4;   // padded, 16B-aligned
        *(float4*)(sB + off) = gB[t];
        *(float4*)(sD + off) = gD[t];
    }
    __syncthreads();

    const int n   = t >> 3;             // component 0..127
    const int sub = t & 7;              // 0..7 (j-pair in w2 phase, point-group in main)

    const float4* B4 = (const float4*)(sB + n * STRIDE);
    const float4* D4 = (const float4*)(sD + n * STRIDE);

    // ---- w2 phase: 8 threads/comp, thread owns j = {2*sub, 2*sub+1} ----
    // relu(min) == min then max-with-0 init (monotone commute).
    {
        const float4 fd = D4[sub];      // (d0[2s], d1[2s], d0[2s+1], d1[2s+1])
        float w = 0.0f;
        #pragma unroll
        for (int q = 0; q < 8; ++q) {
            const float4 fb = B4[q];    // (b0[2q], b1[2q], b0[2q+1], b1[2q+1])
            w = fmaxf(w, fminf(fd.x - fb.x, fd.y - fb.y));
            w = fmaxf(w, fminf(fd.x - fb.z, fd.y - fb.w));
            w = fmaxf(w, fminf(fd.z - fb.x, fd.w - fb.y));
            w = fmaxf(w, fminf(fd.z - fb.z, fd.w - fb.w));
        }
        // reduce across the 8 sub-lanes (contiguous lanes within the wave)
        w = fmaxf(w, __shfl_xor(w, 1));
        w = fmaxf(w, __shfl_xor(w, 2));
        w = fmaxf(w, __shfl_xor(w, 4));
        if (sub == 0) {
            if (!isfinite(w)) w = 0.0f;
            sW2[n] = w * w;
        }
    }
    // NO barrier here: sW2 is only read after the barrier that follows the
    // main db/dd loop below -> the sync cost hides behind ~450 VALU ops.

    // ---- main loop: this thread's comp n vs its 4 grid points ----
    const int p0 = pblk * PTS_PER_BLK + 4 * sub;
    const int i0 = p0 >> 6;             // block-uniform row -> uniform x0
    const float x0 = -3.0f + 6.0f * (float)i0 / 63.0f;
    float x1v[4];
    #pragma unroll
    for (int j = 0; j < 4; ++j)
        x1v[j] = -3.0f + 6.0f * (float)((p0 + j) & 63) / 63.0f;

    // wave: n = lane>>3 -> 8 distinct comps, 8-lane broadcast; comp stride
    // 144 B -> bank groups 0,4,...,28: conflict-free b128 reads.
    float db[4] = {1e30f, 1e30f, 1e30f, 1e30f};
    float dd[4] = {1e30f, 1e30f, 1e30f, 1e30f};
    #pragma unroll 4
    for (int q = 0; q < 8; ++q) {       // 2 boundary points per float4
        const float4 fb = B4[q];
        const float4 fd = D4[q];
        float s  = fb.x - x0;           // shared across the 4 grid points
        float sd = x0 - fd.x;
        #pragma unroll
        for (int j = 0; j < 4; ++j) {
            db[j] = fminf(db[j], fmaxf(s,  fb.y - x1v[j]));
            dd[j] = fminf(dd[j], fmaxf(sd, x1v[j] - fd.y));
        }
        s  = fb.z - x0;
        sd = x0 - fd.z;
        #pragma unroll
        for (int j = 0; j < 4; ++j) {
            db[j] = fminf(db[j], fmaxf(s,  fb.w - x1v[j]));
            dd[j] = fminf(dd[j], fmaxf(sd, x1v[j] - fd.w));
        }
    }

    __syncthreads();                    // sW2 visibility (write was pre-loop)
    const float w2n = sW2[n];           // 8-lane broadcast
    const float cexp = -0.5f / (0.3f * 0.3f);
    #pragma unroll
    for (int j = 0; j < 4; ++j) {
        const float r = fmaxf(fmaxf(db[j], dd[j]), 0.0f);
        // scalar stores, pad 33: exactly 2 lanes/bank = wave64 minimum (free)
        psum[n][4 * sub + j] = __expf(cexp * r * r) * w2n;
    }
    __syncthreads();

    // ---- reduction: 32 points x sum over 128 comps, two LDS stages ----
    if (t < 256) {                      // oct = t>>5 owns 16 comps for point p
        const int p   = t & 31;
        const int oct = t >> 5;
        float s = 0.0f;
        #pragma unroll
        for (int m = 0; m < 16; ++m)    // addr ≡ oct*16+m+p (mod 32): ≤2-way, free
            s += psum[oct * 16 + m][p];
        pp[oct][p] = s;
    }
    __syncthreads();
    if (t < PTS_PER_BLK) {
        float s = 0.0f;
        #pragma unroll
        for (int q = 0; q < 8; ++q) s += pp[q][t];
        out[(size_t)b * NPTS + pblk * PTS_PER_BLK + t] = s;
    }
}

extern "C" void kernel_launch(void* const* d_in, const int* in_sizes, int n_in,
                              void* d_out, int out_size, void* d_ws, size_t ws_size,
                              hipStream_t stream) {
    const float* Bs = (const float*)d_in[0];
    const float* Ds = (const float*)d_in[1];
    float* out = (float*)d_out;
    fused_kernel<<<dim3(NB * 128), dim3(1024), 0, stream>>>(Bs, Ds, out);
}